// Round 14
// baseline (4300.938 us; speedup 1.0000x reference)
//
#include <hip/hip_runtime.h>
#include <hip/hip_bf16.h>

// ws byte layout (12,976,128 B — proven footprint):
//   REG0/REG1: bf16 [64 b][1024 k] @ 0 / 131072 — ring regions 0,1 (zero-init)
//   XT:  bf16 [512][64] @ 262144 (65536 B)  x transposed [t][b] (immutable)
//   BAR: @ 327680: 128B-strided int slots:
//        leaf[i]=+i*128 (i=0..15; 16 WGs/leaf) | root=+16*128
//        xmail[x]=+(17+x)*128 | flag[x]=+(25+x)*128 | xcnt[x]=+(33+x)*128
//   ZERO:@ 366592 (256 B zeros — B-frag source for z1 cols, k>=512 quadrant)
//   WP/RING: @ 393216, 96 x 131072 = 12,582,912 B. init stages hi/lo weights
//        (M1hi+0, M1lo+2097152, M2hi+4194304, M2lo+8388608); lstm loads them to
//        REGISTERS pre-loop; same bytes then recycle as ring regions 2..97.
//   Ring (R13-proven): phase p reads region p%98, writes (p+1)%98 via agent-
//        scope atomic stores (MALL write-through). Readers: plain cached loads.
//   R14: per-XCD leader warms the next region's 2048 lines into its L2 before
//        releasing local WGs -> one MALL read stream per XCD, rest hit L2.
#define XT_B 262144
#define BAR_B 327680
#define ZERO_B 366592
#define WP_B 393216
#define M1HI_B (WP_B + 0)
#define M1LO_B (WP_B + 2097152)
#define M2HI_B (WP_B + 4194304)
#define M2LO_B (WP_B + 8388608)
#define NREG 98
#define REG_BYTES 131072
#define BAR_INTS (41 * 32)
// final h2 (step 511) written at phase 512 -> region 513%98 = 23:
#define FINAL_REG_B (WP_B + (23 - 2) * REG_BYTES)

typedef __attribute__((ext_vector_type(4))) unsigned int uint4v;
typedef __attribute__((ext_vector_type(8))) short short8;     // 8 bf16 (4 VGPRs)
typedef __attribute__((ext_vector_type(4))) float f32x4;
union AF { uint4v u; short8 s; };

__device__ __forceinline__ float sigm(float x) { return 1.f / (1.f + __expf(-x)); }
__device__ __forceinline__ float tanh_f(float x) {
    float a = fabsf(x);
    float e = __expf(-2.f * a);
    float r = (1.f - e) / (1.f + e);
    return copysignf(r, x);
}
__device__ __forceinline__ float bf2f(unsigned int u) {
    union { unsigned int i; float f; } v; v.i = u << 16; return v.f;
}
__device__ __forceinline__ unsigned short f2bf(float f) {
    union { float f; unsigned int i; } v; v.f = f;
    unsigned int u = v.i + 0x7fffu + ((v.i >> 16) & 1u);   // RNE
    return (unsigned short)(u >> 16);
}
__device__ __forceinline__ int reg_off(int r) {
    return (r < 2) ? r * REG_BYTES : WP_B + (r - 2) * REG_BYTES;
}

__global__ void init_kernel(const float* __restrict__ x, const float* __restrict__ W0,
                            const float* __restrict__ W1, char* __restrict__ wsb) {
    unsigned int* Hz = (unsigned int*)wsb;                   // regions 0,1 = 65536 dwords
    unsigned short* XT = (unsigned short*)(wsb + XT_B);
    int* BAR = (int*)(wsb + BAR_B);
    unsigned int* ZP = (unsigned int*)(wsb + ZERO_B);
    unsigned short* M1h = (unsigned short*)(wsb + M1HI_B);
    unsigned short* M1l = (unsigned short*)(wsb + M1LO_B);
    unsigned short* M2h = (unsigned short*)(wsb + M2HI_B);
    unsigned short* M2l = (unsigned short*)(wsb + M2LO_B);
    int i = blockIdx.x * blockDim.x + threadIdx.x;
    int stride = gridDim.x * blockDim.x;
    for (int j = i; j < 65536; j += stride) Hz[j] = 0;
    for (int j = i; j < 32768; j += stride) {
        int p = j >> 6, b = j & 63;
        XT[j] = f2bf(x[b * 512 + p]);
    }
    for (int j = i; j < BAR_INTS; j += stride) BAR[j] = 0;
    for (int j = i; j < 64; j += stride) ZP[j] = 0;
    for (int j = i; j < 2048 * 512; j += stride) {           // M1: W0 recurrent rows 1..512
        int c = j >> 9, k = j & 511;
        float f = W0[(1 + k) * 2048 + c];
        unsigned short hi = f2bf(f);
        unsigned short lo = f2bf(f - bf2f(hi));
        M1h[c * 512 + k] = hi;  M1l[c * 512 + k] = lo;
    }
    for (int j = i; j < 2048 * 1024; j += stride) {          // M2: W1 full
        int c = j >> 10, k = j & 1023;
        float f = W1[k * 2048 + c];
        unsigned short hi = f2bf(f);
        unsigned short lo = f2bf(f - bf2f(hi));
        M2h[c * 1024 + k] = hi;  M2l[c * 1024 + k] = lo;
    }
}

// R14 barrier: arrive (leaf->root RMW, R6-proven) -> root-finisher stores 8
// xmail slots -> per-XCD leader polls xmail, WARMS the next region into its
// XCD's L2 (plain loads, one merged MALL stream), stores flag[xcd] -> 31 local
// WGs poll flag[xcd], then read h as L2 hits. All counters MALL write-through.
__device__ __forceinline__ void grid_bar_warm(char* __restrict__ wsb, int* bar,
        int epoch, int warm_off, int bx, int t, int leader, int xcd) {
    __syncthreads();                       // drains h stores (vmcnt 0 -> at MALL)
    int* leaf  = bar + (bx >> 4) * 32;
    int* root  = bar + 16 * 32;
    int* xmail = bar + (17 + xcd) * 32;
    int* flag  = bar + (25 + xcd) * 32;
    const int target = 16 * (epoch + 1);
    if (t == 0) {
        int old = __hip_atomic_fetch_add(leaf, 1, __ATOMIC_RELAXED, __HIP_MEMORY_SCOPE_AGENT);
        if (old == target - 1) {
            int ro = __hip_atomic_fetch_add(root, 1, __ATOMIC_RELAXED, __HIP_MEMORY_SCOPE_AGENT);
            if (ro == target - 1) {
                #pragma unroll
                for (int x = 0; x < 8; ++x)
                    __hip_atomic_store(bar + (17 + x) * 32, epoch + 1,
                                       __ATOMIC_RELAXED, __HIP_MEMORY_SCOPE_AGENT);
            }
        }
    }
    if (leader) {
        if (t == 0) {
            while (__hip_atomic_load(xmail, __ATOMIC_RELAXED, __HIP_MEMORY_SCOPE_AGENT) < epoch + 1)
                __builtin_amdgcn_s_sleep(1);
        }
        __syncthreads();
        // warm 2048 lines (131072 B): thread t touches lines t, t+512, t+1024, t+1536
        {
            const char* p0 = wsb + warm_off + t * 64;
            const char* p1 = p0 + 32768;
            const char* p2 = p0 + 65536;
            const char* p3 = p0 + 98304;
            unsigned int d0, d1, d2, d3;
            asm volatile(
                "global_load_dword %0, %4, off\n\t"
                "global_load_dword %1, %5, off\n\t"
                "global_load_dword %2, %6, off\n\t"
                "global_load_dword %3, %7, off\n\t"
                "s_waitcnt vmcnt(0)"
                : "=&v"(d0), "=&v"(d1), "=&v"(d2), "=&v"(d3)
                : "v"(p0), "v"(p1), "v"(p2), "v"(p3)
                : "memory");
        }
        __syncthreads();
        if (t == 0)
            __hip_atomic_store(flag, epoch + 1, __ATOMIC_RELAXED, __HIP_MEMORY_SCOPE_AGENT);
    } else {
        if (t == 0) {
            while (__hip_atomic_load(flag, __ATOMIC_RELAXED, __HIP_MEMORY_SCOPE_AGENT) < epoch + 1)
                __builtin_amdgcn_s_sleep(1);
        }
        __syncthreads();
    }
}

__global__ __launch_bounds__(512) void lstm_kernel(char* __restrict__ wsb,
        const float* __restrict__ W0, const float* __restrict__ b0,
        const float* __restrict__ b1) {
    __shared__ float red[8 * 16 * 76];   // [wave][n][b], stride 76
    __shared__ int sh_leader;

    const int t = threadIdx.x, bx = blockIdx.x;
    const int b = t & 63;
    const int lane = t & 63;
    const int w = __builtin_amdgcn_readfirstlane(t >> 6);    // wave id = K-slice owner
    const int n = lane & 15, q = lane >> 4;

    int xcd;
    asm("s_getreg_b32 %0, hwreg(HW_REG_XCC_ID)" : "=s"(xcd));
    xcd &= 7;

    const unsigned short* XT = (const unsigned short*)(wsb + XT_B);
    int* BAR = (int*)(wsb + BAR_B);

    // ---- one-time: B-frags (weights) into registers: hi+lo bf16 = exact fp32 ----
    short8 Bhi[4], Blo[4];
    {
        int nn = (n < 8) ? n : (n - 8);
        int colb = ((nn >> 1) << 9) + 2 * bx + (nn & 1);
        #pragma unroll
        for (int s = 0; s < 4; ++s) {
            int k_loc = w * 128 + s * 32 + q * 8;
            const short8 *phi, *plo;
            if (n < 8) {            // z1 cols: W0r for k<512, zero quadrant above
                if (k_loc < 512) {
                    phi = (const short8*)(wsb + M1HI_B + (colb * 512 + k_loc) * 2);
                    plo = (const short8*)(wsb + M1LO_B + (colb * 512 + k_loc) * 2);
                } else {
                    phi = (const short8*)(wsb + ZERO_B + q * 16);
                    plo = phi;
                }
            } else {                // z2 cols: W1 full K
                phi = (const short8*)(wsb + M2HI_B + (colb * 1024 + k_loc) * 2);
                plo = (const short8*)(wsb + M2LO_B + (colb * 1024 + k_loc) * 2);
            }
            Bhi[s] = *phi;  Blo[s] = *plo;
        }
    }
    // Pin B-frags in registers before the staging bytes are recycled as ring.
    asm volatile("" : "+v"(Bhi[0]), "+v"(Bhi[1]), "+v"(Bhi[2]), "+v"(Bhi[3]),
                      "+v"(Blo[0]), "+v"(Blo[1]), "+v"(Blo[2]), "+v"(Blo[3]) :: "memory");

    // ---- one-time: per-XCD leader election (R10-proven) ----
    if (t == 0) {
        int rk = __hip_atomic_fetch_add(BAR + (33 + xcd) * 32, 1,
                                        __ATOMIC_RELAXED, __HIP_MEMORY_SCOPE_AGENT);
        sh_leader = (rk == 0) ? 1 : 0;
    }

    // cell threads: t<128 -> (layer l = t>>6, batch b)
    const int cell_l = t >> 6;
    float cs0 = 0.f, cs1 = 0.f;
    float bi0 = 0, bi1 = 0, bj0 = 0, bj1 = 0, bf0 = 0, bf1 = 0, bo0 = 0, bo1 = 0;
    float wxi0 = 0, wxi1 = 0, wxj0 = 0, wxj1 = 0, wxf0 = 0, wxf1 = 0, wxo0 = 0, wxo1 = 0;
    if (t < 128) {
        int u0 = bx * 2, u1 = bx * 2 + 1;
        const float* bb = (cell_l == 0) ? b0 : b1;
        bi0 = bb[u0];            bi1 = bb[u1];
        bj0 = bb[512 + u0];      bj1 = bb[512 + u1];
        bf0 = bb[1024 + u0];     bf1 = bb[1024 + u1];
        bo0 = bb[1536 + u0];     bo1 = bb[1536 + u1];
        if (cell_l == 0) {
            wxi0 = W0[u0];          wxi1 = W0[u1];
            wxj0 = W0[512 + u0];    wxj1 = W0[512 + u1];
            wxf0 = W0[1024 + u0];   wxf1 = W0[1024 + u1];
            wxo0 = W0[1536 + u0];   wxo1 = W0[1536 + u1];
        }
    }
    __syncthreads();                   // publish sh_leader
    const int leader = sh_leader;

    // Pre-loop barrier (epoch 0): weights consumed; leader warms region 0.
    grid_bar_warm(wsb, BAR, 0, reg_off(0), bx, t, leader, xcd);

    // A-frag per-lane byte offset within a region: row (lane&15), k-slice (w,q)
    const int base_a = (lane & 15) * 2048 + w * 256 + q * 16;

    int rd = 0;                       // read region = p % 98
    for (int p = 0; p <= 512; ++p) {
        const int wr = (rd + 1 == NREG) ? 0 : rd + 1;
        // ---- A-frags: plain cached loads (L2-warm via leader). One asm block:
        //      16 loads + waitcnt, early-clobber (R12 NaN fix). ----
        const char* hb = wsb + reg_off(rd) + base_a;
        const char* hr0 = hb;
        const char* hr1 = hb + 32768;
        const char* hr2 = hb + 65536;
        const char* hr3 = hb + 98304;
        uint4v av[4][4];
        asm volatile(
            "global_load_dwordx4 %0, %16, off\n\t"
            "global_load_dwordx4 %1, %16, off offset:64\n\t"
            "global_load_dwordx4 %2, %16, off offset:128\n\t"
            "global_load_dwordx4 %3, %16, off offset:192\n\t"
            "global_load_dwordx4 %4, %17, off\n\t"
            "global_load_dwordx4 %5, %17, off offset:64\n\t"
            "global_load_dwordx4 %6, %17, off offset:128\n\t"
            "global_load_dwordx4 %7, %17, off offset:192\n\t"
            "global_load_dwordx4 %8, %18, off\n\t"
            "global_load_dwordx4 %9, %18, off offset:64\n\t"
            "global_load_dwordx4 %10, %18, off offset:128\n\t"
            "global_load_dwordx4 %11, %18, off offset:192\n\t"
            "global_load_dwordx4 %12, %19, off\n\t"
            "global_load_dwordx4 %13, %19, off offset:64\n\t"
            "global_load_dwordx4 %14, %19, off offset:128\n\t"
            "global_load_dwordx4 %15, %19, off offset:192\n\t"
            "s_waitcnt vmcnt(0)"
            : "=&v"(av[0][0]), "=&v"(av[0][1]), "=&v"(av[0][2]), "=&v"(av[0][3]),
              "=&v"(av[1][0]), "=&v"(av[1][1]), "=&v"(av[1][2]), "=&v"(av[1][3]),
              "=&v"(av[2][0]), "=&v"(av[2][1]), "=&v"(av[2][2]), "=&v"(av[2][3]),
              "=&v"(av[3][0]), "=&v"(av[3][1]), "=&v"(av[3][2]), "=&v"(av[3][3])
            : "v"(hr0), "v"(hr1), "v"(hr2), "v"(hr3)
            : "memory");

        // ---- MFMA: D[64 b x 16 n] partial over this wave's K=128 slice ----
        f32x4 acc[4];
        #pragma unroll
        for (int mt = 0; mt < 4; ++mt) acc[mt] = (f32x4){0.f, 0.f, 0.f, 0.f};
        #pragma unroll
        for (int s = 0; s < 4; ++s) {
            #pragma unroll
            for (int mt = 0; mt < 4; ++mt) {
                AF af; af.u = av[mt][s];
                acc[mt] = __builtin_amdgcn_mfma_f32_16x16x32_bf16(af.s, Bhi[s], acc[mt], 0, 0, 0);
                acc[mt] = __builtin_amdgcn_mfma_f32_16x16x32_bf16(af.s, Blo[s], acc[mt], 0, 0, 0);
            }
        }
        // C layout: col n = lane&15, row b = mt*16 + q*4 + reg  ->  red[w][n][b]
        #pragma unroll
        for (int mt = 0; mt < 4; ++mt) {
            float* dst = red + (w * 16 + n) * 76 + mt * 16 + q * 4;
            *(f32x4*)dst = acc[mt];
        }
        float xv = (t < 64 && p < 512) ? bf2f((unsigned int)XT[p * 64 + b]) : 0.f;
        __syncthreads();
        // ---- cell update (t<128), publish h to MALL (ring region wr) ----
        if (t < 128) {
            bool active = (cell_l == 0) ? (p < 512) : (p >= 1);
            if (active) {
                float zi0 = bi0, zi1 = bi1, zj0 = bj0, zj1 = bj1;
                float zf0 = bf0, zf1 = bf1, zo0 = bo0, zo1 = bo1;
                const int nb = cell_l * 8;
                #pragma unroll
                for (int ww = 0; ww < 8; ++ww) {
                    const float* rp = red + (ww * 16 + nb) * 76 + b;
                    zi0 += rp[0];        zi1 += rp[76];
                    zj0 += rp[2 * 76];   zj1 += rp[3 * 76];
                    zf0 += rp[4 * 76];   zf1 += rp[5 * 76];
                    zo0 += rp[6 * 76];   zo1 += rp[7 * 76];
                }
                if (cell_l == 0) {
                    zi0 += xv * wxi0; zi1 += xv * wxi1;
                    zj0 += xv * wxj0; zj1 += xv * wxj1;
                    zf0 += xv * wxf0; zf1 += xv * wxf1;
                    zo0 += xv * wxo0; zo1 += xv * wxo1;
                }
                cs0 = cs0 * sigm(zf0 + 1.f) + sigm(zi0) * tanh_f(zj0);
                cs1 = cs1 * sigm(zf1 + 1.f) + sigm(zi1) * tanh_f(zj1);
                float h0 = tanh_f(cs0) * sigm(zo0);
                float h1 = tanh_f(cs1) * sigm(zo1);
                unsigned int packed = (unsigned int)f2bf(h0)
                                    | ((unsigned int)f2bf(h1) << 16);
                unsigned int* dst = (unsigned int*)(wsb + reg_off(wr))
                                  + b * 512 + cell_l * 256 + bx;
                __hip_atomic_store(dst, packed, __ATOMIC_RELAXED, __HIP_MEMORY_SCOPE_AGENT);
            }
        }
        // ---- barrier + leader warm of region wr ----
        grid_bar_warm(wsb, BAR, p + 1, reg_off(wr), bx, t, leader, xcd);
        rd = wr;
    }
}

__global__ void logits_kernel(const char* __restrict__ wsb, const float* __restrict__ sw,
                              const float* __restrict__ sb, float* __restrict__ out) {
    // final h2 = h2[511], written at phase 512 -> region 23, rows [b][512+k]
    const unsigned short* Hs = (const unsigned short*)(wsb + FINAL_REG_B);
    int c = blockIdx.x, b = threadIdx.x;
    float acc = 0.f;
    for (int k = 0; k < 512; ++k)
        acc += bf2f((unsigned int)Hs[b * 1024 + 512 + k]) * sw[k * 10 + c];
    out[b * 10 + c] = acc + sb[c];
}

extern "C" void kernel_launch(void* const* d_in, const int* in_sizes, int n_in,
                              void* d_out, int out_size, void* d_ws, size_t ws_size,
                              hipStream_t stream) {
    (void)in_sizes; (void)n_in; (void)out_size; (void)ws_size;
    const float* x  = (const float*)d_in[0];
    const float* W0 = (const float*)d_in[1];
    const float* b0 = (const float*)d_in[2];
    const float* W1 = (const float*)d_in[3];
    const float* b1 = (const float*)d_in[4];
    const float* sw = (const float*)d_in[5];
    const float* sb = (const float*)d_in[6];
    char* wsb  = (char*)d_ws;
    float* out = (float*)d_out;

    hipLaunchKernelGGL(init_kernel, dim3(1024), dim3(256), 0, stream, x, W0, W1, wsb);

    char* wsb_p = wsb;
    const float* W0_p = W0;
    const float* b0_p = b0;
    const float* b1_p = b1;
    void* args[] = { &wsb_p, &W0_p, &b0_p, &b1_p };
    (void)hipLaunchCooperativeKernel((void*)lstm_kernel, dim3(256), dim3(512), args, 0, stream);

    hipLaunchKernelGGL(logits_kernel, dim3(10), dim3(64), 0, stream, wsb, sw, sb, out);
}

// Round 18
// 3606.786 us; speedup vs baseline: 1.1925x; 1.1925x over previous
//
#include <hip/hip_runtime.h>
#include <hip/hip_bf16.h>

// ws byte layout (12,976,128 B — proven footprint):
//   REG0/REG1: bf16 [64 b][1024 k] @ 0 / 131072 — ring regions 0,1 (zero-init;
//              serve phases 0,1 before the weight area is recycled)
//   XT:  bf16 [512][64] @ 262144 (65536 B)  x transposed [t][b] (immutable)
//   BAR: @ 327680 (34944 B): leaf[i]=+i*128 (16 WGs/leaf) | root=+16*128
//        mail[w]=+(17+w)*128 (w=0..255)   — R6 fan-out barrier, epoch-monotone
//   ZERO:@ 366592 (256 B zeros — B-frag source for z1 cols, k>=512 quadrant)
//   WP/RING: @ 393216, 96 x 131072 = 12,582,912 B.
//        init_kernel stages hi/lo weights here (M1hi@+0, M1lo@+2097152,
//        M2hi@+4194304, M2lo@+8388608); lstm_kernel loads them into REGISTERS
//        pre-loop, then the SAME bytes become ring regions 2..97.
//   Ring: phase p reads region p%98 ({h1[p-1] k<512, h2[p-2] k>=512}, [b][1024k]),
//        writes region (p+1)%98 via agent-scope atomic dword stores (MALL
//        write-through, proven R5+). Readers use PLAIN cached loads: a region's
//        addresses were last written 98 phases ago; ~12.5 MB of fills churn each
//        4 MB 16-way L2 in between (128 KB region stride -> every set turns over
//        ~3x), so stale lines are structurally evicted. No fences, no buffer_inv.
#define XT_B 262144
#define BAR_B 327680
#define ZERO_B 366592
#define WP_B 393216
#define M1HI_B (WP_B + 0)
#define M1LO_B (WP_B + 2097152)
#define M2HI_B (WP_B + 4194304)
#define M2LO_B (WP_B + 8388608)
#define NREG 98
#define REG_BYTES 131072
#define BAR_INTS (273 * 32)
// final h2 (step 511) written at phase 512 -> region 513%98 = 23 -> base:
#define FINAL_REG_B (WP_B + (23 - 2) * REG_BYTES)   // = 3,145,728

typedef __attribute__((ext_vector_type(4))) unsigned int uint4v;
typedef __attribute__((ext_vector_type(8))) short short8;     // 8 bf16 (4 VGPRs)
typedef __attribute__((ext_vector_type(4))) float f32x4;
union AF { uint4v u; short8 s; };

__device__ __forceinline__ float sigm(float x) { return 1.f / (1.f + __expf(-x)); }
__device__ __forceinline__ float tanh_f(float x) {
    float a = fabsf(x);
    float e = __expf(-2.f * a);
    float r = (1.f - e) / (1.f + e);
    return copysignf(r, x);
}
__device__ __forceinline__ float bf2f(unsigned int u) {
    union { unsigned int i; float f; } v; v.i = u << 16; return v.f;
}
__device__ __forceinline__ unsigned short f2bf(float f) {
    union { float f; unsigned int i; } v; v.f = f;
    unsigned int u = v.i + 0x7fffu + ((v.i >> 16) & 1u);   // RNE
    return (unsigned short)(u >> 16);
}
__device__ __forceinline__ int reg_off(int r) {
    return (r < 2) ? r * REG_BYTES : WP_B + (r - 2) * REG_BYTES;
}

__global__ void init_kernel(const float* __restrict__ x, const float* __restrict__ W0,
                            const float* __restrict__ W1, char* __restrict__ wsb) {
    unsigned int* Hz = (unsigned int*)wsb;                   // regions 0,1 = 65536 dwords
    unsigned short* XT = (unsigned short*)(wsb + XT_B);
    int* BAR = (int*)(wsb + BAR_B);
    unsigned int* ZP = (unsigned int*)(wsb + ZERO_B);
    unsigned short* M1h = (unsigned short*)(wsb + M1HI_B);
    unsigned short* M1l = (unsigned short*)(wsb + M1LO_B);
    unsigned short* M2h = (unsigned short*)(wsb + M2HI_B);
    unsigned short* M2l = (unsigned short*)(wsb + M2LO_B);
    int i = blockIdx.x * blockDim.x + threadIdx.x;
    int stride = gridDim.x * blockDim.x;
    for (int j = i; j < 65536; j += stride) Hz[j] = 0;
    for (int j = i; j < 32768; j += stride) {
        int p = j >> 6, b = j & 63;
        XT[j] = f2bf(x[b * 512 + p]);
    }
    for (int j = i; j < BAR_INTS; j += stride) BAR[j] = 0;
    for (int j = i; j < 64; j += stride) ZP[j] = 0;
    for (int j = i; j < 2048 * 512; j += stride) {           // M1: W0 recurrent rows 1..512
        int c = j >> 9, k = j & 511;
        float f = W0[(1 + k) * 2048 + c];
        unsigned short hi = f2bf(f);
        unsigned short lo = f2bf(f - bf2f(hi));
        M1h[c * 512 + k] = hi;  M1l[c * 512 + k] = lo;
    }
    for (int j = i; j < 2048 * 1024; j += stride) {          // M2: W1 full
        int c = j >> 10, k = j & 1023;
        float f = W1[k * 2048 + c];
        unsigned short hi = f2bf(f);
        unsigned short lo = f2bf(f - bf2f(hi));
        M2h[c * 1024 + k] = hi;  M2l[c * 1024 + k] = lo;
    }
}

// R6 fan-out barrier (proven): leaf RMW -> root RMW -> broadcaster wave stores
// 256 per-WG mailboxes (1 poller/line). Epochs monotone. No fences needed: h
// stores are MALL write-through, drained (vmcnt 0) at __syncthreads before arrive.
__device__ __forceinline__ void grid_bar(int* bar, int epoch, int bx, int t) {
    __syncthreads();
    if (t < 64) {
        int* leaf = bar + (bx >> 4) * 32;
        int* root = bar + 16 * 32;
        int* mailbase = bar + 17 * 32;
        int target = 16 * (epoch + 1);
        int isB = 0;
        if (t == 0) {
            int old = __hip_atomic_fetch_add(leaf, 1, __ATOMIC_RELAXED, __HIP_MEMORY_SCOPE_AGENT);
            if (old == target - 1) {
                int ro = __hip_atomic_fetch_add(root, 1, __ATOMIC_RELAXED, __HIP_MEMORY_SCOPE_AGENT);
                if (ro == target - 1) isB = 1;
            }
        }
        isB = __builtin_amdgcn_readfirstlane(isB);
        if (isB) {
            #pragma unroll
            for (int r = 0; r < 4; ++r)
                __hip_atomic_store(mailbase + (r * 64 + t) * 32, epoch + 1,
                                   __ATOMIC_RELAXED, __HIP_MEMORY_SCOPE_AGENT);
        }
        if (t == 0) {
            int* my = mailbase + bx * 32;
            while (__hip_atomic_load(my, __ATOMIC_RELAXED, __HIP_MEMORY_SCOPE_AGENT) < epoch + 1)
                __builtin_amdgcn_s_sleep(1);
        }
    }
    __syncthreads();
}

__global__ __launch_bounds__(512) void lstm_kernel(char* __restrict__ wsb,
        const float* __restrict__ W0, const float* __restrict__ b0,
        const float* __restrict__ b1) {
    __shared__ float red[8 * 16 * 76];   // [wave][n][b], stride 76

    const int t = threadIdx.x, bx = blockIdx.x;
    const int b = t & 63;
    const int lane = t & 63;
    const int w = __builtin_amdgcn_readfirstlane(t >> 6);    // wave id = K-slice owner
    const int n = lane & 15, q = lane >> 4;

    const unsigned short* XT = (const unsigned short*)(wsb + XT_B);
    int* BAR = (int*)(wsb + BAR_B);

    // ---- one-time: B-frags (weights) into registers: hi+lo bf16 = exact fp32 ----
    short8 Bhi[4], Blo[4];
    {
        int nn = (n < 8) ? n : (n - 8);
        int colb = ((nn >> 1) << 9) + 2 * bx + (nn & 1);
        #pragma unroll
        for (int s = 0; s < 4; ++s) {
            int k_loc = w * 128 + s * 32 + q * 8;
            const short8 *phi, *plo;
            if (n < 8) {            // z1 cols: W0r for k<512, zero quadrant above
                if (k_loc < 512) {
                    phi = (const short8*)(wsb + M1HI_B + (colb * 512 + k_loc) * 2);
                    plo = (const short8*)(wsb + M1LO_B + (colb * 512 + k_loc) * 2);
                } else {
                    phi = (const short8*)(wsb + ZERO_B + q * 16);
                    plo = phi;
                }
            } else {                // z2 cols: W1 full K
                phi = (const short8*)(wsb + M2HI_B + (colb * 1024 + k_loc) * 2);
                plo = (const short8*)(wsb + M2LO_B + (colb * 1024 + k_loc) * 2);
            }
            Bhi[s] = *phi;  Blo[s] = *plo;
        }
    }
    // Pin B-frags in registers NOW: the staging bytes are recycled as ring
    // regions after the pre-loop barrier; the compiler must not sink the loads.
    asm volatile("" : "+v"(Bhi[0]), "+v"(Bhi[1]), "+v"(Bhi[2]), "+v"(Bhi[3]),
                      "+v"(Blo[0]), "+v"(Blo[1]), "+v"(Blo[2]), "+v"(Blo[3]) :: "memory");

    // cell threads: t<128 -> (layer l = t>>6, batch b)
    const int cell_l = t >> 6;
    float cs0 = 0.f, cs1 = 0.f;
    float bi0 = 0, bi1 = 0, bj0 = 0, bj1 = 0, bf0 = 0, bf1 = 0, bo0 = 0, bo1 = 0;
    float wxi0 = 0, wxi1 = 0, wxj0 = 0, wxj1 = 0, wxf0 = 0, wxf1 = 0, wxo0 = 0, wxo1 = 0;
    if (t < 128) {
        int u0 = bx * 2, u1 = bx * 2 + 1;
        const float* bb = (cell_l == 0) ? b0 : b1;
        bi0 = bb[u0];            bi1 = bb[u1];
        bj0 = bb[512 + u0];      bj1 = bb[512 + u1];
        bf0 = bb[1024 + u0];     bf1 = bb[1024 + u1];
        bo0 = bb[1536 + u0];     bo1 = bb[1536 + u1];
        if (cell_l == 0) {
            wxi0 = W0[u0];          wxi1 = W0[u1];
            wxj0 = W0[512 + u0];    wxj1 = W0[512 + u1];
            wxf0 = W0[1024 + u0];   wxf1 = W0[1024 + u1];
            wxo0 = W0[1536 + u0];   wxo1 = W0[1536 + u1];
        }
    }

    // Pre-loop grid barrier (epoch 0): all WGs have consumed the weight bytes.
    grid_bar(BAR, 0, bx, t);

    // A-frag per-lane byte offset within a region: row (lane&15), k-slice (w,q)
    const int base_a = (lane & 15) * 2048 + w * 256 + q * 16;

    int rd = 0;                       // read region = p % 98
    for (int p = 0; p <= 512; ++p) {
        const int wr = (rd + 1 == NREG) ? 0 : rd + 1;
        // ---- A-frags: PLAIN cached loads (ring freshness, no inv needed).
        //      One asm block: 16 loads + waitcnt, early-clobber (R12 NaN fix). ----
        const char* hb = wsb + reg_off(rd) + base_a;
        const char* hr0 = hb;
        const char* hr1 = hb + 32768;
        const char* hr2 = hb + 65536;
        const char* hr3 = hb + 98304;
        uint4v av[4][4];
        asm volatile(
            "global_load_dwordx4 %0, %16, off\n\t"
            "global_load_dwordx4 %1, %16, off offset:64\n\t"
            "global_load_dwordx4 %2, %16, off offset:128\n\t"
            "global_load_dwordx4 %3, %16, off offset:192\n\t"
            "global_load_dwordx4 %4, %17, off\n\t"
            "global_load_dwordx4 %5, %17, off offset:64\n\t"
            "global_load_dwordx4 %6, %17, off offset:128\n\t"
            "global_load_dwordx4 %7, %17, off offset:192\n\t"
            "global_load_dwordx4 %8, %18, off\n\t"
            "global_load_dwordx4 %9, %18, off offset:64\n\t"
            "global_load_dwordx4 %10, %18, off offset:128\n\t"
            "global_load_dwordx4 %11, %18, off offset:192\n\t"
            "global_load_dwordx4 %12, %19, off\n\t"
            "global_load_dwordx4 %13, %19, off offset:64\n\t"
            "global_load_dwordx4 %14, %19, off offset:128\n\t"
            "global_load_dwordx4 %15, %19, off offset:192\n\t"
            "s_waitcnt vmcnt(0)"
            : "=&v"(av[0][0]), "=&v"(av[0][1]), "=&v"(av[0][2]), "=&v"(av[0][3]),
              "=&v"(av[1][0]), "=&v"(av[1][1]), "=&v"(av[1][2]), "=&v"(av[1][3]),
              "=&v"(av[2][0]), "=&v"(av[2][1]), "=&v"(av[2][2]), "=&v"(av[2][3]),
              "=&v"(av[3][0]), "=&v"(av[3][1]), "=&v"(av[3][2]), "=&v"(av[3][3])
            : "v"(hr0), "v"(hr1), "v"(hr2), "v"(hr3)
            : "memory");

        // ---- MFMA: D[64 b x 16 n] partial over this wave's K=128 slice ----
        f32x4 acc[4];
        #pragma unroll
        for (int mt = 0; mt < 4; ++mt) acc[mt] = (f32x4){0.f, 0.f, 0.f, 0.f};
        #pragma unroll
        for (int s = 0; s < 4; ++s) {
            #pragma unroll
            for (int mt = 0; mt < 4; ++mt) {
                AF af; af.u = av[mt][s];
                acc[mt] = __builtin_amdgcn_mfma_f32_16x16x32_bf16(af.s, Bhi[s], acc[mt], 0, 0, 0);
                acc[mt] = __builtin_amdgcn_mfma_f32_16x16x32_bf16(af.s, Blo[s], acc[mt], 0, 0, 0);
            }
        }
        // C layout: col n = lane&15, row b = mt*16 + q*4 + reg  ->  red[w][n][b]
        #pragma unroll
        for (int mt = 0; mt < 4; ++mt) {
            float* dst = red + (w * 16 + n) * 76 + mt * 16 + q * 4;
            *(f32x4*)dst = acc[mt];
        }
        float xv = (t < 64 && p < 512) ? bf2f((unsigned int)XT[p * 64 + b]) : 0.f;
        __syncthreads();
        // ---- cell update (t<128), publish h to MALL (ring region wr) ----
        if (t < 128) {
            bool active = (cell_l == 0) ? (p < 512) : (p >= 1);
            if (active) {
                float zi0 = bi0, zi1 = bi1, zj0 = bj0, zj1 = bj1;
                float zf0 = bf0, zf1 = bf1, zo0 = bo0, zo1 = bo1;
                const int nb = cell_l * 8;
                #pragma unroll
                for (int ww = 0; ww < 8; ++ww) {
                    const float* rp = red + (ww * 16 + nb) * 76 + b;
                    zi0 += rp[0];        zi1 += rp[76];
                    zj0 += rp[2 * 76];   zj1 += rp[3 * 76];
                    zf0 += rp[4 * 76];   zf1 += rp[5 * 76];
                    zo0 += rp[6 * 76];   zo1 += rp[7 * 76];
                }
                if (cell_l == 0) {
                    zi0 += xv * wxi0; zi1 += xv * wxi1;
                    zj0 += xv * wxj0; zj1 += xv * wxj1;
                    zf0 += xv * wxf0; zf1 += xv * wxf1;
                    zo0 += xv * wxo0; zo1 += xv * wxo1;
                }
                cs0 = cs0 * sigm(zf0 + 1.f) + sigm(zi0) * tanh_f(zj0);
                cs1 = cs1 * sigm(zf1 + 1.f) + sigm(zi1) * tanh_f(zj1);
                float h0 = tanh_f(cs0) * sigm(zo0);
                float h1 = tanh_f(cs1) * sigm(zo1);
                unsigned int packed = (unsigned int)f2bf(h0)
                                    | ((unsigned int)f2bf(h1) << 16);
                unsigned int* dst = (unsigned int*)(wsb + reg_off(wr))
                                  + b * 512 + cell_l * 256 + bx;
                __hip_atomic_store(dst, packed, __ATOMIC_RELAXED, __HIP_MEMORY_SCOPE_AGENT);
            }
        }
        // ---- barrier (R6 fan-out; __syncthreads inside drains h stores) ----
        grid_bar(BAR, p + 1, bx, t);
        rd = wr;
    }
}

__global__ void logits_kernel(const char* __restrict__ wsb, const float* __restrict__ sw,
                              const float* __restrict__ sb, float* __restrict__ out) {
    // final h2 = h2[511], written at phase 512 -> region 23, rows [b][512+k]
    const unsigned short* Hs = (const unsigned short*)(wsb + FINAL_REG_B);
    int c = blockIdx.x, b = threadIdx.x;
    float acc = 0.f;
    for (int k = 0; k < 512; ++k)
        acc += bf2f((unsigned int)Hs[b * 1024 + 512 + k]) * sw[k * 10 + c];
    out[b * 10 + c] = acc + sb[c];
}

extern "C" void kernel_launch(void* const* d_in, const int* in_sizes, int n_in,
                              void* d_out, int out_size, void* d_ws, size_t ws_size,
                              hipStream_t stream) {
    (void)in_sizes; (void)n_in; (void)out_size; (void)ws_size;
    const float* x  = (const float*)d_in[0];
    const float* W0 = (const float*)d_in[1];
    const float* b0 = (const float*)d_in[2];
    const float* W1 = (const float*)d_in[3];
    const float* b1 = (const float*)d_in[4];
    const float* sw = (const float*)d_in[5];
    const float* sb = (const float*)d_in[6];
    char* wsb  = (char*)d_ws;
    float* out = (float*)d_out;

    hipLaunchKernelGGL(init_kernel, dim3(1024), dim3(256), 0, stream, x, W0, W1, wsb);

    char* wsb_p = wsb;
    const float* W0_p = W0;
    const float* b0_p = b0;
    const float* b1_p = b1;
    void* args[] = { &wsb_p, &W0_p, &b0_p, &b1_p };
    (void)hipLaunchCooperativeKernel((void*)lstm_kernel, dim3(256), dim3(512), args, 0, stream);

    hipLaunchKernelGGL(logits_kernel, dim3(10), dim3(64), 0, stream, wsb, sw, sb, out);
}